// Round 8
// baseline (217.107 us; speedup 1.0000x reference)
//
#include <hip/hip_runtime.h>

// 2-layer tanh RNN, fused, f32, single-wave blocks, no barriers.
// B=4096 chains, T=512 steps, H=20.
// R8 = R7 design with the macro bug fixed (FMA4's param `w` collided with
// float4 member `.w`; now inline functions, no token capture):
//  - ALL per-lane weights and h-tiles as NAMED float4 SSA values -> true
//    VGPR residency (~180 VGPRs) instead of scratch-backed arrays.
//  - GB=6 batches/wave, 2 adjacent output rows per lane: 10 ds_read_b128
//    per iter serve 6 batches -> half the per-batch LDS bandwidth.
//  - xs rows padded to 516 floats (conflict-free x reads).

#define Bsz 4096
#define Tn  512
#define Hn  20
#define GB  6                  // batches per wave
#define LPB 10                 // lanes per batch (2 output rows each)
#define XPAD 516               // 516%32=4 -> per-row bank offset, 16B-aligned
#define NTHREADS 64

__device__ __forceinline__ float tanh_fast(float v) {
    // tanh(v) = 1 - 2/(exp(2v)+1); v_exp_f32 + v_rcp_f32.
    float e = __expf(2.0f * v);
    return 1.0f - 2.0f * __builtin_amdgcn_rcpf(e + 1.0f);
}

__device__ __forceinline__ float fma4(float4 a, float4 b, float acc) {
    acc = fmaf(a.x, b.x, acc); acc = fmaf(a.y, b.y, acc);
    acc = fmaf(a.z, b.z, acc); acc = fmaf(a.w, b.w, acc);
    return acc;
}

// 20-element dot: two chains (chunks 0,2,4 and 1,3), caller adds cA+cB.
__device__ __forceinline__ void dot20(float& cA, float& cB,
                                      float4 w0, float4 w1, float4 w2,
                                      float4 w3, float4 w4,
                                      float4 h0, float4 h1, float4 h2,
                                      float4 h3, float4 h4) {
    cA = fma4(w0, h0, cA); cB = fma4(w1, h1, cB); cA = fma4(w2, h2, cA);
    cB = fma4(w3, h3, cB); cA = fma4(w4, h4, cA);
}

__global__ __launch_bounds__(NTHREADS, 1)
void rnn2_fused(const float* __restrict__ x,        // [B,T,1]
                const float* __restrict__ hidden,   // [2,B,H]
                const float* __restrict__ W_ih0,    // [H,1]
                const float* __restrict__ W_hh0,    // [H,H]
                const float* __restrict__ b_ih0,    // [H]
                const float* __restrict__ b_hh0,    // [H]
                const float* __restrict__ W_ih1,    // [H,H]
                const float* __restrict__ W_hh1,    // [H,H]
                const float* __restrict__ b_ih1,    // [H]
                const float* __restrict__ b_hh1,    // [H]
                const float* __restrict__ fc_w,     // [1,H]
                const float* __restrict__ fc_b,     // [1]
                float* __restrict__ out)            // [B] ++ [2,B,H] flat
{
    const int tid = threadIdx.x;
    int g  = tid / LPB;                // 0..6
    int jj = tid - g * LPB;            // 0..9
    if (g >= GB) { g = GB - 1; jj = tid - 60; }   // lanes 60..63 dup (5,0..3)
    const int j0 = 2 * jj;             // my even output row (j0, j0+1)

    const int  b        = blockIdx.x * GB + g;
    const bool b_ok     = (b < Bsz);
    const int  bl       = b_ok ? b : (Bsz - 1);
    const bool store_ok = (tid < GB * LPB) && b_ok;

    __shared__ float xs[GB][XPAD];     // 12.4 KB
    __shared__ float h0s[2][GB][Hn];   // double-buffered hidden state
    __shared__ float h1s[2][GB][Hn];

    // stage ALL x up front (coalesced float4; clamp batch index)
    {
        const int bB = blockIdx.x * GB;
        #pragma unroll
        for (int r = 0; r < (GB * Tn) / (NTHREADS * 4); ++r) {  // 12 rounds
            const int c  = (r * NTHREADS + tid) * 4;
            const int gg = c >> 9;            // c / 512
            const int t  = c & (Tn - 1);      // c % 512
            const int bb = (bB + gg < Bsz) ? (bB + gg) : (Bsz - 1);
            float4 v = *(const float4*)(x + (long)bb * Tn + t);
            *(float4*)&xs[gg][t] = v;
        }
    }

    // per-lane weights: rows j0, j0+1 of the 3 HxH matrices, as 30 named
    // float4 SSA values (120 scalars) -> VGPR-resident.
    const float4* pw0e = (const float4*)(W_hh0 + j0 * Hn);
    const float4* pw0o = (const float4*)(W_hh0 + (j0 + 1) * Hn);
    const float4* pw1e = (const float4*)(W_ih1 + j0 * Hn);
    const float4* pw1o = (const float4*)(W_ih1 + (j0 + 1) * Hn);
    const float4* pw2e = (const float4*)(W_hh1 + j0 * Hn);
    const float4* pw2o = (const float4*)(W_hh1 + (j0 + 1) * Hn);
    const float4 w0e0 = pw0e[0], w0e1 = pw0e[1], w0e2 = pw0e[2], w0e3 = pw0e[3], w0e4 = pw0e[4];
    const float4 w0o0 = pw0o[0], w0o1 = pw0o[1], w0o2 = pw0o[2], w0o3 = pw0o[3], w0o4 = pw0o[4];
    const float4 w1e0 = pw1e[0], w1e1 = pw1e[1], w1e2 = pw1e[2], w1e3 = pw1e[3], w1e4 = pw1e[4];
    const float4 w1o0 = pw1o[0], w1o1 = pw1o[1], w1o2 = pw1o[2], w1o3 = pw1o[3], w1o4 = pw1o[4];
    const float4 w2e0 = pw2e[0], w2e1 = pw2e[1], w2e2 = pw2e[2], w2e3 = pw2e[3], w2e4 = pw2e[4];
    const float4 w2o0 = pw2o[0], w2o1 = pw2o[1], w2o2 = pw2o[2], w2o3 = pw2o[3], w2o4 = pw2o[4];

    const float wih0e = W_ih0[j0],  wih0o = W_ih0[j0 + 1];
    const float b0e = b_ih0[j0]     + b_hh0[j0];
    const float b0o = b_ih0[j0 + 1] + b_hh0[j0 + 1];
    const float b1e = b_ih1[j0]     + b_hh1[j0];
    const float b1o = b_ih1[j0 + 1] + b_hh1[j0 + 1];

    // init: h0 -> buf0; h1 -> buf0 AND buf1 (layer1 first reads buf1 at
    // i=1, which i=0 does not write). j0 even -> 8B-aligned float2.
    {
        float2 h0i = *(const float2*)(hidden + bl * Hn + j0);
        float2 h1i = *(const float2*)(hidden + (long)Bsz * Hn + bl * Hn + j0);
        *(float2*)&h0s[0][g][j0] = h0i;
        *(float2*)&h1s[0][g][j0] = h1i;
        *(float2*)&h1s[1][g][j0] = h1i;
    }
    // single-wave in-order DS pipe: later reads see these writes, no barrier

    // iter i: layer0 computes h0[i] (i<T), layer1 computes h1[i-1] (i>0).
    // reads buf p=i&1 (h0[i-1], h1[i-2]); writes buf p^1. No barriers.
    #pragma unroll 2
    for (int i = 0; i <= Tn; ++i) {
        const int p = i & 1, q = p ^ 1;

        // h-state tiles as named float4 SSA values (broadcast b128 reads)
        const float4 h00 = *(const float4*)&h0s[p][g][0];
        const float4 h01 = *(const float4*)&h0s[p][g][4];
        const float4 h02 = *(const float4*)&h0s[p][g][8];
        const float4 h03 = *(const float4*)&h0s[p][g][12];
        const float4 h04 = *(const float4*)&h0s[p][g][16];
        const float4 h10 = *(const float4*)&h1s[p][g][0];
        const float4 h11 = *(const float4*)&h1s[p][g][4];
        const float4 h12 = *(const float4*)&h1s[p][g][8];
        const float4 h13 = *(const float4*)&h1s[p][g][12];
        const float4 h14 = *(const float4*)&h1s[p][g][16];

        const float xt = xs[g][(i < Tn) ? i : (Tn - 1)];

        float a0eA = fmaf(xt, wih0e, b0e), a0eB = 0.f;
        float a0oA = fmaf(xt, wih0o, b0o), a0oB = 0.f;
        float a1eA = b1e, a1eB = 0.f;
        float a1oA = b1o, a1oB = 0.f;
        float a2eA = 0.f, a2eB = 0.f;
        float a2oA = 0.f, a2oB = 0.f;

        dot20(a0eA, a0eB, w0e0, w0e1, w0e2, w0e3, w0e4, h00, h01, h02, h03, h04);
        dot20(a0oA, a0oB, w0o0, w0o1, w0o2, w0o3, w0o4, h00, h01, h02, h03, h04);
        dot20(a1eA, a1eB, w1e0, w1e1, w1e2, w1e3, w1e4, h00, h01, h02, h03, h04);
        dot20(a1oA, a1oB, w1o0, w1o1, w1o2, w1o3, w1o4, h00, h01, h02, h03, h04);
        dot20(a2eA, a2eB, w2e0, w2e1, w2e2, w2e3, w2e4, h10, h11, h12, h13, h14);
        dot20(a2oA, a2oB, w2o0, w2o1, w2o2, w2o3, w2o4, h10, h11, h12, h13, h14);

        if (i < Tn) {
            float2 n0 = make_float2(tanh_fast(a0eA + a0eB),
                                    tanh_fast(a0oA + a0oB));
            *(float2*)&h0s[q][g][j0] = n0;       // ds_write_b64
        }
        if (i > 0) {
            float2 n1 = make_float2(tanh_fast((a1eA + a1eB) + (a2eA + a2eB)),
                                    tanh_fast((a1oA + a1oB) + (a2oA + a2oB)));
            *(float2*)&h1s[q][g][j0] = n1;       // ds_write_b64
        }
    }

    // final states: h0[511] written at i=511 -> buf0; h1[511] at i=512 -> buf1
    if (store_ok) {
        *(float2*)(out + Bsz + (long)b * Hn + j0) =
            *(const float2*)&h0s[0][g][j0];                       // new_hidden[0]
        *(float2*)(out + Bsz + (long)Bsz * Hn + (long)b * Hn + j0) =
            *(const float2*)&h1s[1][g][j0];                       // new_hidden[1]
        if (jj == 0) {                 // fc head: one lane per batch
            const float4 f0 = ((const float4*)fc_w)[0];
            const float4 f1 = ((const float4*)fc_w)[1];
            const float4 f2 = ((const float4*)fc_w)[2];
            const float4 f3 = ((const float4*)fc_w)[3];
            const float4 f4 = ((const float4*)fc_w)[4];
            const float4 v0 = *(const float4*)&h1s[1][g][0];
            const float4 v1 = *(const float4*)&h1s[1][g][4];
            const float4 v2 = *(const float4*)&h1s[1][g][8];
            const float4 v3 = *(const float4*)&h1s[1][g][12];
            const float4 v4 = *(const float4*)&h1s[1][g][16];
            float accA = fc_b[0], accB = 0.f;
            accA = fma4(f0, v0, accA); accB = fma4(f1, v1, accB);
            accA = fma4(f2, v2, accA); accB = fma4(f3, v3, accB);
            accA = fma4(f4, v4, accA);
            out[b] = accA + accB;
        }
    }
}

extern "C" void kernel_launch(void* const* d_in, const int* in_sizes, int n_in,
                              void* d_out, int out_size, void* d_ws, size_t ws_size,
                              hipStream_t stream) {
    const float* x      = (const float*)d_in[0];
    const float* hidden = (const float*)d_in[1];
    const float* W_ih0  = (const float*)d_in[2];
    const float* W_hh0  = (const float*)d_in[3];
    const float* b_ih0  = (const float*)d_in[4];
    const float* b_hh0  = (const float*)d_in[5];
    const float* W_ih1  = (const float*)d_in[6];
    const float* W_hh1  = (const float*)d_in[7];
    const float* b_ih1  = (const float*)d_in[8];
    const float* b_hh1  = (const float*)d_in[9];
    const float* fc_w   = (const float*)d_in[10];
    const float* fc_b   = (const float*)d_in[11];

    const int nblocks = (Bsz + GB - 1) / GB;   // 683
    rnn2_fused<<<nblocks, NTHREADS, 0, stream>>>(
        x, hidden, W_ih0, W_hh0, b_ih0, b_hh0,
        W_ih1, W_hh1, b_ih1, b_hh1, fc_w, fc_b, (float*)d_out);
}

// Round 9
// 189.354 us; speedup vs baseline: 1.1466x; 1.1466x over previous
//
#include <hip/hip_runtime.h>

// 2-layer tanh RNN, fused, f32, single-wave blocks, no barriers,
// SINGLE-buffer LDS state, rolled loop. B=4096, T=512, H=20.
// R9 rationale:
//  - GB=6 (2 adjacent output rows/lane, 10 lanes/batch): halves DS-pipe
//    work per batch vs GB=3 (10 ds_read_b128 serve 6 batches).
//  - Single buffer hs[layer][g][j]: within one wave the DS pipe is in-order
//    (validated R6), so iter i+1's reads (issued after iter i's writes) are
//    RAW-safe; iter i's reads precede its writes in program order (WAR-safe).
//    Removes double-buffer p/q => rolled loop, constant addresses.
//  - Rolled tiny body + peeled prologue/epilogue => 30 loop-invariant
//    float4 weights can stay VGPR-resident (R8's unroll-2 + dbuf spilled
//    them; VGPR=104). Target VGPR >= 170.
//  - x pre-staged in LDS (padded rows), zero global ops in loop.

#define Bsz 4096
#define Tn  512
#define Hn  20
#define GB  6                  // batches per wave
#define LPB 10                 // lanes per batch (2 output rows each)
#define XPAD 516               // x row stride: conflict-free group reads
#define NTHREADS 64

__device__ __forceinline__ float tanh_fast(float v) {
    // tanh(v) = 1 - 2/(exp(2v)+1); v_exp_f32 + v_rcp_f32.
    float e = __expf(2.0f * v);
    return 1.0f - 2.0f * __builtin_amdgcn_rcpf(e + 1.0f);
}

__device__ __forceinline__ float fma4(float4 a, float4 b, float acc) {
    acc = fmaf(a.x, b.x, acc); acc = fmaf(a.y, b.y, acc);
    acc = fmaf(a.z, b.z, acc); acc = fmaf(a.w, b.w, acc);
    return acc;
}

__global__ __launch_bounds__(NTHREADS, 1)
void rnn2_fused(const float* __restrict__ x,        // [B,T,1]
                const float* __restrict__ hidden,   // [2,B,H]
                const float* __restrict__ W_ih0,    // [H,1]
                const float* __restrict__ W_hh0,    // [H,H]
                const float* __restrict__ b_ih0,    // [H]
                const float* __restrict__ b_hh0,    // [H]
                const float* __restrict__ W_ih1,    // [H,H]
                const float* __restrict__ W_hh1,    // [H,H]
                const float* __restrict__ b_ih1,    // [H]
                const float* __restrict__ b_hh1,    // [H]
                const float* __restrict__ fc_w,     // [1,H]
                const float* __restrict__ fc_b,     // [1]
                float* __restrict__ out)            // [B] ++ [2,B,H] flat
{
    const int tid = threadIdx.x;
    int g  = tid / LPB;                // 0..6
    int jj = tid - g * LPB;            // 0..9
    if (g >= GB) { g = GB - 1; jj = tid - 60; }   // lanes 60..63: dup rows of
    const int j0 = 2 * jj;             // batch 5 (same addr+data, benign)

    const int  b        = blockIdx.x * GB + g;
    const bool b_ok     = (b < Bsz);
    const int  bl       = b_ok ? b : (Bsz - 1);
    const bool store_ok = (tid < GB * LPB) && b_ok;

    __shared__ float xs[GB][XPAD];     // 12.4 KB
    __shared__ float hs[2][GB][Hn];    // SINGLE-buffer state: [layer][g][j]

    // ---- weights first: 30 loop-invariant float4 SSA values (issue early)
    const float4* pw0e = (const float4*)(W_hh0 + j0 * Hn);
    const float4* pw0o = (const float4*)(W_hh0 + (j0 + 1) * Hn);
    const float4* pw1e = (const float4*)(W_ih1 + j0 * Hn);
    const float4* pw1o = (const float4*)(W_ih1 + (j0 + 1) * Hn);
    const float4* pw2e = (const float4*)(W_hh1 + j0 * Hn);
    const float4* pw2o = (const float4*)(W_hh1 + (j0 + 1) * Hn);
    const float4 w0e0 = pw0e[0], w0e1 = pw0e[1], w0e2 = pw0e[2], w0e3 = pw0e[3], w0e4 = pw0e[4];
    const float4 w0o0 = pw0o[0], w0o1 = pw0o[1], w0o2 = pw0o[2], w0o3 = pw0o[3], w0o4 = pw0o[4];
    const float4 w1e0 = pw1e[0], w1e1 = pw1e[1], w1e2 = pw1e[2], w1e3 = pw1e[3], w1e4 = pw1e[4];
    const float4 w1o0 = pw1o[0], w1o1 = pw1o[1], w1o2 = pw1o[2], w1o3 = pw1o[3], w1o4 = pw1o[4];
    const float4 w2e0 = pw2e[0], w2e1 = pw2e[1], w2e2 = pw2e[2], w2e3 = pw2e[3], w2e4 = pw2e[4];
    const float4 w2o0 = pw2o[0], w2o1 = pw2o[1], w2o2 = pw2o[2], w2o3 = pw2o[3], w2o4 = pw2o[4];

    const float wih0e = W_ih0[j0],  wih0o = W_ih0[j0 + 1];
    const float b0e = b_ih0[j0]     + b_hh0[j0];
    const float b0o = b_ih0[j0 + 1] + b_hh0[j0 + 1];
    const float b1e = b_ih1[j0]     + b_hh1[j0];
    const float b1o = b_ih1[j0 + 1] + b_hh1[j0 + 1];

    // ---- stage ALL x (coalesced float4; clamped batch rows)
    {
        const int bB = blockIdx.x * GB;
        #pragma unroll
        for (int r = 0; r < (GB * Tn) / (NTHREADS * 4); ++r) {  // 12 rounds
            const int c  = (r * NTHREADS + tid) * 4;
            const int gg = c >> 9;            // c / 512
            const int t  = c & (Tn - 1);      // c % 512
            const int bb = (bB + gg < Bsz) ? (bB + gg) : (Bsz - 1);
            float4 v = *(const float4*)(x + (long)bb * Tn + t);
            *(float4*)&xs[gg][t] = v;
        }
    }

    // ---- init state: hs[0] = h0[-1], hs[1] = h1[-1]
    {
        float2 h0i = *(const float2*)(hidden + bl * Hn + j0);
        float2 h1i = *(const float2*)(hidden + (long)Bsz * Hn + bl * Hn + j0);
        *(float2*)&hs[0][g][j0] = h0i;
        *(float2*)&hs[1][g][j0] = h1i;
    }
    // single-wave in-order DS pipe: later reads see these writes

    // ---- prologue (i=0): h0[0] = tanh(W_hh0 h0[-1] + x0 wih0 + b0)
    {
        const float4 h00 = *(const float4*)&hs[0][g][0];
        const float4 h01 = *(const float4*)&hs[0][g][4];
        const float4 h02 = *(const float4*)&hs[0][g][8];
        const float4 h03 = *(const float4*)&hs[0][g][12];
        const float4 h04 = *(const float4*)&hs[0][g][16];
        const float xt = xs[g][0];
        float a0e = fmaf(xt, wih0e, b0e), a0o = fmaf(xt, wih0o, b0o);
        a0e = fma4(w0e0,h00, a0e); a0e = fma4(w0e1,h01, a0e); a0e = fma4(w0e2,h02, a0e);
        a0e = fma4(w0e3,h03, a0e); a0e = fma4(w0e4,h04, a0e);
        a0o = fma4(w0o0,h00, a0o); a0o = fma4(w0o1,h01, a0o); a0o = fma4(w0o2,h02, a0o);
        a0o = fma4(w0o3,h03, a0o); a0o = fma4(w0o4,h04, a0o);
        *(float2*)&hs[0][g][j0] = make_float2(tanh_fast(a0e), tanh_fast(a0o));
    }

    // ---- main loop i=1..511: hs[0]=h0[i-1], hs[1]=h1[i-2] on entry;
    // computes h0[i] and h1[i-1]; writes both. Rolled, branchless body.
    #pragma unroll 1
    for (int i = 1; i < Tn; ++i) {
        const float4 h00 = *(const float4*)&hs[0][g][0];
        const float4 h01 = *(const float4*)&hs[0][g][4];
        const float4 h02 = *(const float4*)&hs[0][g][8];
        const float4 h03 = *(const float4*)&hs[0][g][12];
        const float4 h04 = *(const float4*)&hs[0][g][16];
        const float4 h10 = *(const float4*)&hs[1][g][0];
        const float4 h11 = *(const float4*)&hs[1][g][4];
        const float4 h12 = *(const float4*)&hs[1][g][8];
        const float4 h13 = *(const float4*)&hs[1][g][12];
        const float4 h14 = *(const float4*)&hs[1][g][16];

        const float xt = xs[g][i];

        float a0e = fmaf(xt, wih0e, b0e), a0o = fmaf(xt, wih0o, b0o);
        float a1e = b1e, a1o = b1o;
        float a2e = 0.f, a2o = 0.f;
        a0e = fma4(w0e0,h00, a0e); a0e = fma4(w0e1,h01, a0e); a0e = fma4(w0e2,h02, a0e);
        a0e = fma4(w0e3,h03, a0e); a0e = fma4(w0e4,h04, a0e);
        a0o = fma4(w0o0,h00, a0o); a0o = fma4(w0o1,h01, a0o); a0o = fma4(w0o2,h02, a0o);
        a0o = fma4(w0o3,h03, a0o); a0o = fma4(w0o4,h04, a0o);
        a1e = fma4(w1e0,h00, a1e); a1e = fma4(w1e1,h01, a1e); a1e = fma4(w1e2,h02, a1e);
        a1e = fma4(w1e3,h03, a1e); a1e = fma4(w1e4,h04, a1e);
        a1o = fma4(w1o0,h00, a1o); a1o = fma4(w1o1,h01, a1o); a1o = fma4(w1o2,h02, a1o);
        a1o = fma4(w1o3,h03, a1o); a1o = fma4(w1o4,h04, a1o);
        a2e = fma4(w2e0,h10, a2e); a2e = fma4(w2e1,h11, a2e); a2e = fma4(w2e2,h12, a2e);
        a2e = fma4(w2e3,h13, a2e); a2e = fma4(w2e4,h14, a2e);
        a2o = fma4(w2o0,h10, a2o); a2o = fma4(w2o1,h11, a2o); a2o = fma4(w2o2,h12, a2o);
        a2o = fma4(w2o3,h13, a2o); a2o = fma4(w2o4,h14, a2o);

        const float2 n0 = make_float2(tanh_fast(a0e), tanh_fast(a0o));
        const float2 n1 = make_float2(tanh_fast(a1e + a2e), tanh_fast(a1o + a2o));
        *(float2*)&hs[0][g][j0] = n0;   // h0[i]
        *(float2*)&hs[1][g][j0] = n1;   // h1[i-1]
    }

    // ---- epilogue (i=512): h1[511] from h0[511], h1[510]
    {
        const float4 h00 = *(const float4*)&hs[0][g][0];
        const float4 h01 = *(const float4*)&hs[0][g][4];
        const float4 h02 = *(const float4*)&hs[0][g][8];
        const float4 h03 = *(const float4*)&hs[0][g][12];
        const float4 h04 = *(const float4*)&hs[0][g][16];
        const float4 h10 = *(const float4*)&hs[1][g][0];
        const float4 h11 = *(const float4*)&hs[1][g][4];
        const float4 h12 = *(const float4*)&hs[1][g][8];
        const float4 h13 = *(const float4*)&hs[1][g][12];
        const float4 h14 = *(const float4*)&hs[1][g][16];
        float a1e = b1e, a1o = b1o, a2e = 0.f, a2o = 0.f;
        a1e = fma4(w1e0,h00, a1e); a1e = fma4(w1e1,h01, a1e); a1e = fma4(w1e2,h02, a1e);
        a1e = fma4(w1e3,h03, a1e); a1e = fma4(w1e4,h04, a1e);
        a1o = fma4(w1o0,h00, a1o); a1o = fma4(w1o1,h01, a1o); a1o = fma4(w1o2,h02, a1o);
        a1o = fma4(w1o3,h03, a1o); a1o = fma4(w1o4,h04, a1o);
        a2e = fma4(w2e0,h10, a2e); a2e = fma4(w2e1,h11, a2e); a2e = fma4(w2e2,h12, a2e);
        a2e = fma4(w2e3,h13, a2e); a2e = fma4(w2e4,h14, a2e);
        a2o = fma4(w2o0,h10, a2o); a2o = fma4(w2o1,h11, a2o); a2o = fma4(w2o2,h12, a2o);
        a2o = fma4(w2o3,h13, a2o); a2o = fma4(w2o4,h14, a2o);
        *(float2*)&hs[1][g][j0] =
            make_float2(tanh_fast(a1e + a2e), tanh_fast(a1o + a2o));
    }

    // ---- outputs: hs[0]=h0[511], hs[1]=h1[511]
    if (store_ok) {
        *(float2*)(out + Bsz + (long)b * Hn + j0) =
            *(const float2*)&hs[0][g][j0];                        // new_hidden[0]
        *(float2*)(out + Bsz + (long)Bsz * Hn + (long)b * Hn + j0) =
            *(const float2*)&hs[1][g][j0];                        // new_hidden[1]
        if (jj == 0) {                 // fc head: one lane per batch
            const float4 f0 = ((const float4*)fc_w)[0];
            const float4 f1 = ((const float4*)fc_w)[1];
            const float4 f2 = ((const float4*)fc_w)[2];
            const float4 f3 = ((const float4*)fc_w)[3];
            const float4 f4 = ((const float4*)fc_w)[4];
            const float4 v0 = *(const float4*)&hs[1][g][0];
            const float4 v1 = *(const float4*)&hs[1][g][4];
            const float4 v2 = *(const float4*)&hs[1][g][8];
            const float4 v3 = *(const float4*)&hs[1][g][12];
            const float4 v4 = *(const float4*)&hs[1][g][16];
            float accA = fc_b[0], accB = 0.f;
            accA = fma4(f0, v0, accA); accB = fma4(f1, v1, accB);
            accA = fma4(f2, v2, accA); accB = fma4(f3, v3, accB);
            accA = fma4(f4, v4, accA);
            out[b] = accA + accB;
        }
    }
}

extern "C" void kernel_launch(void* const* d_in, const int* in_sizes, int n_in,
                              void* d_out, int out_size, void* d_ws, size_t ws_size,
                              hipStream_t stream) {
    const float* x      = (const float*)d_in[0];
    const float* hidden = (const float*)d_in[1];
    const float* W_ih0  = (const float*)d_in[2];
    const float* W_hh0  = (const float*)d_in[3];
    const float* b_ih0  = (const float*)d_in[4];
    const float* b_hh0  = (const float*)d_in[5];
    const float* W_ih1  = (const float*)d_in[6];
    const float* W_hh1  = (const float*)d_in[7];
    const float* b_ih1  = (const float*)d_in[8];
    const float* b_hh1  = (const float*)d_in[9];
    const float* fc_w   = (const float*)d_in[10];
    const float* fc_b   = (const float*)d_in[11];

    const int nblocks = (Bsz + GB - 1) / GB;   // 683
    rnn2_fused<<<nblocks, NTHREADS, 0, stream>>>(
        x, hidden, W_ih0, W_hh0, b_ih0, b_hh0,
        W_ih1, W_hh1, b_ih1, b_hh1, fc_w, fc_b, (float*)d_out);
}